// Round 4
// baseline (592.705 us; speedup 1.0000x reference)
//
#include <hip/hip_runtime.h>

// RoIAlign forward, Detectron-style, sampling_ratio = 2.
// features: [N=2, C=256, H=200, W=200] fp32 ; rois: [1000,5] ; out: [1000,256,7,7]
//
// R4: (a) float4-vectorized NCHW->NHWC transpose (R3's scalar version ran at
// 1.4 TB/s, ~120us); (b) main kernel = one block per roi: all 784 tap reads
// and the roi's whole 50 KB output come from one CU, so L2 merges the
// channel-major stores into full lines (R3 had 3.3x write amplification from
// cross-CU scatter). Per-axis sample idx/weights precomputed in LDS.

#define POOLED_H 7
#define POOLED_W 7
#define SPATIAL_SCALE 0.0625f
#define FEAT_N 2
#define FEAT_C 256
#define FEAT_H 200
#define FEAT_W 200
#define FEAT_S (FEAT_H * FEAT_W)          // 40000
#define FEAT_SC ((size_t)FEAT_S * FEAT_C) // 10.24M floats per batch image

// ---------------- transpose NCHW -> NHWC (float4 both ways) ----------------
__global__ __launch_bounds__(256) void nchw_to_nhwc(const float* __restrict__ in,
                                                    float* __restrict__ outp) {
    __shared__ float t[64][65];
    const int s0 = blockIdx.x * 64;   // 625 spatial tiles (exact)
    const int c0 = blockIdx.y * 64;   // 4 channel tiles (exact)
    const int b = blockIdx.z;
    const int g = threadIdx.x & 15;   // 16-lane group index
    const int rr = threadIdx.x >> 4;  // 0..15
    // load: row = channel, 16 lanes x float4 = 256 B contiguous along spatial
    const float* ip = in + ((size_t)(b * FEAT_C + c0)) * FEAT_S + s0;
#pragma unroll
    for (int k = 0; k < 4; ++k) {
        int c = rr + k * 16;
        float4 v = *(const float4*)(ip + (size_t)c * FEAT_S + g * 4);
        t[c][g * 4 + 0] = v.x;
        t[c][g * 4 + 1] = v.y;
        t[c][g * 4 + 2] = v.z;
        t[c][g * 4 + 3] = v.w;
    }
    __syncthreads();
    // store: row = spatial, 16 lanes x float4 = 256 B contiguous along channel
    float* op = outp + ((size_t)b * FEAT_S + s0) * FEAT_C + c0;
#pragma unroll
    for (int k = 0; k < 4; ++k) {
        int s = rr + k * 16;
        float4 v;
        v.x = t[g * 4 + 0][s];
        v.y = t[g * 4 + 1][s];
        v.z = t[g * 4 + 2][s];
        v.w = t[g * 4 + 3][s];
        *(float4*)(op + (size_t)s * FEAT_C + g * 4) = v;
    }
}

// ---------------- main kernel: one block per roi ----------------
__global__ __launch_bounds__(256, 4) void roialign_main(
    const float* __restrict__ feat,   // [N,H,W,C]
    const float* __restrict__ rois,
    float* __restrict__ out,
    int num_rois) {
    __shared__ int s_ylo[14], s_yhi[14], s_xlo[14], s_xhi[14];
    __shared__ float s_ywl[14], s_ywh[14], s_xwl[14], s_xwh[14];

    const int roi = blockIdx.x;
    const float* r = rois + roi * 5;
    const int b = (int)r[0];
    const float x1 = r[1] * SPATIAL_SCALE;
    const float y1 = r[2] * SPATIAL_SCALE;
    const float x2 = r[3] * SPATIAL_SCALE;
    const float y2 = r[4] * SPATIAL_SCALE;
    const float bin_w = fmaxf(x2 - x1, 1.0f) * (1.0f / POOLED_W);
    const float bin_h = fmaxf(y2 - y1, 1.0f) * (1.0f / POOLED_H);

    const int tid = threadIdx.x;
    // per-axis sample precompute: 14 y-samples by threads 0..13,
    // 14 x-samples by threads 64..77 (different wave, runs in parallel)
    if (tid < 14) {
        int p = tid >> 1, i = tid & 1;
        float yy = y1 + (float)p * bin_h + ((float)i + 0.5f) * bin_h * 0.5f;
        bool v = (yy > -1.0f) && (yy < (float)FEAT_H);
        float y = fmaxf(yy, 0.0f);
        int lo = min((int)floorf(y), FEAT_H - 1);
        int hi = min(lo + 1, FEAT_H - 1);
        if (lo >= FEAT_H - 1) y = (float)lo;   // edge snap (reference-exact)
        float l = y - (float)lo;
        s_ylo[tid] = lo;
        s_yhi[tid] = hi;
        s_ywl[tid] = v ? l : 0.0f;             // fold validity into weights
        s_ywh[tid] = v ? (1.0f - l) : 0.0f;
    } else if (tid >= 64 && tid < 78) {
        int tt = tid - 64;
        int p = tt >> 1, i = tt & 1;
        float xx = x1 + (float)p * bin_w + ((float)i + 0.5f) * bin_w * 0.5f;
        bool v = (xx > -1.0f) && (xx < (float)FEAT_W);
        float x = fmaxf(xx, 0.0f);
        int lo = min((int)floorf(x), FEAT_W - 1);
        int hi = min(lo + 1, FEAT_W - 1);
        if (lo >= FEAT_W - 1) x = (float)lo;
        float l = x - (float)lo;
        s_xlo[tt] = lo;
        s_xhi[tt] = hi;
        s_xwl[tt] = v ? l : 0.0f;
        s_xwh[tt] = v ? (1.0f - l) : 0.0f;
    }
    __syncthreads();

    const int lane = tid & 63;   // channel group: channels 4*lane .. 4*lane+3
    const int q = tid >> 6;      // wave id: handles cells s with s%4 == q
    const float* base = feat + (size_t)b * FEAT_SC + (size_t)lane * 4;

    float4 acc[13];
#pragma unroll
    for (int k = 0; k < 13; ++k) acc[k] = float4{0.f, 0.f, 0.f, 0.f};

#pragma unroll
    for (int k = 0; k < 13; ++k) {
        const int s = 4 * k + q;
        if (s < 49) {
            const int ph = (s * 37) >> 8;   // s/7 for s<49
            const int pw = s - ph * 7;
#pragma unroll
            for (int iy = 0; iy < 2; ++iy) {
                const int ky = ph * 2 + iy;
                const int rl = s_ylo[ky] * FEAT_W;
                const int rh = s_yhi[ky] * FEAT_W;
                const float wyl = s_ywl[ky];
                const float wyh = s_ywh[ky];
#pragma unroll
                for (int ix = 0; ix < 2; ++ix) {
                    const int kx = pw * 2 + ix;
                    const int cl = s_xlo[kx];
                    const int ch = s_xhi[kx];
                    const float wxl = s_xwl[kx];
                    const float wxh = s_xwh[kx];
                    const float4 v00 = *(const float4*)(base + (size_t)(rl + cl) * FEAT_C);
                    const float4 v01 = *(const float4*)(base + (size_t)(rl + ch) * FEAT_C);
                    const float4 v10 = *(const float4*)(base + (size_t)(rh + cl) * FEAT_C);
                    const float4 v11 = *(const float4*)(base + (size_t)(rh + ch) * FEAT_C);
                    const float w00 = wyh * wxh, w01 = wyh * wxl;
                    const float w10 = wyl * wxh, w11 = wyl * wxl;
                    acc[k].x += w00 * v00.x + w01 * v01.x + w10 * v10.x + w11 * v11.x;
                    acc[k].y += w00 * v00.y + w01 * v01.y + w10 * v10.y + w11 * v11.y;
                    acc[k].z += w00 * v00.z + w01 * v01.z + w10 * v10.z + w11 * v11.z;
                    acc[k].w += w00 * v00.w + w01 * v01.w + w10 * v10.w + w11 * v11.w;
                }
            }
        }
    }

    // stores: channel-major out[roi, 4*lane+j, s]; whole 50 KB region is
    // written by this block alone -> L2 merges into full lines
    float* ob = out + (size_t)roi * (FEAT_C * 49) + (size_t)lane * 4 * 49;
#pragma unroll
    for (int k = 0; k < 13; ++k) {
        const int s = 4 * k + q;
        if (s < 49) {
            ob[s] = acc[k].x * 0.25f;
            ob[49 + s] = acc[k].y * 0.25f;
            ob[98 + s] = acc[k].z * 0.25f;
            ob[147 + s] = acc[k].w * 0.25f;
        }
    }
}

// ---------------- fallback (direct gather, no workspace) ----------------
__device__ __forceinline__ float bilinear_tap(const float* __restrict__ plane,
                                              float y, float x) {
    const int H = FEAT_H, W = FEAT_W;
    if (!(y > -1.0f && y < (float)H && x > -1.0f && x < (float)W)) return 0.0f;
    y = fmaxf(y, 0.0f);
    x = fmaxf(x, 0.0f);
    int y0 = min((int)floorf(y), H - 1);
    int x0 = min((int)floorf(x), W - 1);
    int y1 = min(y0 + 1, H - 1);
    int x1 = min(x0 + 1, W - 1);
    if (y0 >= H - 1) y = (float)y0;
    if (x0 >= W - 1) x = (float)x0;
    float ly = y - (float)y0, lx = x - (float)x0;
    float hy = 1.0f - ly, hx = 1.0f - lx;
    return hy * (hx * plane[y0 * W + x0] + lx * plane[y0 * W + x1]) +
           ly * (hx * plane[y1 * W + x0] + lx * plane[y1 * W + x1]);
}

__global__ __launch_bounds__(256) void roialign_direct(
    const float* __restrict__ features, const float* __restrict__ rois,
    float* __restrict__ out, int num_rois) {
    int i = blockIdx.x * blockDim.x + threadIdx.x;
    int total = num_rois * FEAT_C * 49;
    if (i >= total) return;
    int s = i % 49;
    int t = i / 49;
    int c = t % FEAT_C;
    int roi = t / FEAT_C;
    int ph = s / POOLED_W, pw = s % POOLED_W;
    const float* r = rois + roi * 5;
    int b = (int)r[0];
    float x1 = r[1] * SPATIAL_SCALE, y1 = r[2] * SPATIAL_SCALE;
    float x2 = r[3] * SPATIAL_SCALE, y2 = r[4] * SPATIAL_SCALE;
    float bin_w = fmaxf(x2 - x1, 1.0f) * (1.0f / POOLED_W);
    float bin_h = fmaxf(y2 - y1, 1.0f) * (1.0f / POOLED_H);
    const float* plane = features + ((size_t)(b * FEAT_C + c)) * FEAT_S;
    float acc = 0.0f;
#pragma unroll
    for (int iy = 0; iy < 2; ++iy) {
        float yy = y1 + (float)ph * bin_h + ((float)iy + 0.5f) * bin_h * 0.5f;
#pragma unroll
        for (int ix = 0; ix < 2; ++ix) {
            float xx = x1 + (float)pw * bin_w + ((float)ix + 0.5f) * bin_w * 0.5f;
            acc += bilinear_tap(plane, yy, xx);
        }
    }
    out[i] = acc * 0.25f;
}

extern "C" void kernel_launch(void* const* d_in, const int* in_sizes, int n_in,
                              void* d_out, int out_size, void* d_ws, size_t ws_size,
                              hipStream_t stream) {
    const float* features = (const float*)d_in[0];
    const float* rois = (const float*)d_in[1];
    float* out = (float*)d_out;
    int num_rois = in_sizes[1] / 5;
    size_t need = (size_t)FEAT_N * FEAT_SC * sizeof(float);  // 81.92 MB
    if (ws_size >= need) {
        float* nhwc = (float*)d_ws;
        nchw_to_nhwc<<<dim3(FEAT_S / 64, FEAT_C / 64, FEAT_N), 256, 0, stream>>>(
            features, nhwc);
        roialign_main<<<num_rois, 256, 0, stream>>>(nhwc, rois, out, num_rois);
    } else {
        int total = num_rois * FEAT_C * 49;
        roialign_direct<<<(total + 255) / 256, 256, 0, stream>>>(features, rois, out,
                                                                 num_rois);
    }
}

// Round 5
// 192.197 us; speedup vs baseline: 3.0838x; 3.0838x over previous
//
#include <hip/hip_runtime.h>

// RoIAlign forward, Detectron-style, sampling_ratio = 2.
// features: [N=2, C=256, H=200, W=200] fp32 ; rois: [1000,5] ; out: [1000,256,7,7]
//
// R5: (a) bf16 NHWC intermediate (41 MB, fits MALL; halves traffic; abs err
// ~0.01 vs 0.065 threshold). (b) Transpose tiled 64ch x 500sp: 2 KB page-run
// reads, page-local 128 B line writes (R4's 256 B @160KB-stride reads were
// DRAM-page-miss-bound at 1.3 TB/s). (c) Main: block = (roi, 64-ch quarter),
// acc -> LDS -> flat float4 stores (1 KB/wave-instr) so the 15x write
// amplification of R4 is structurally impossible; 4000 blocks restore
// occupancy and bound rois-in-flight.

#define POOLED_H 7
#define POOLED_W 7
#define SPATIAL_SCALE 0.0625f
#define FEAT_N 2
#define FEAT_C 256
#define FEAT_H 200
#define FEAT_W 200
#define FEAT_S (FEAT_H * FEAT_W)               // 40000
#define IMG_USH ((size_t)FEAT_S * FEAT_C)      // ushorts per image in NHWC

// transpose tile
#define ST 500            // spatial floats per tile (40000/500 = 80 exact)
#define ST4 (ST / 4)      // 125 float4 per channel row
#define SROW 502          // LDS row stride in ushorts: 251 dwords (odd -> conflict-free gathers)

__device__ __forceinline__ unsigned short f2bf(float f) {
    unsigned int u = __float_as_uint(f);
    u += 0x7fffu + ((u >> 16) & 1u);   // round-to-nearest-even
    return (unsigned short)(u >> 16);
}

// ---------- NCHW fp32 -> NHWC bf16 ----------
__global__ __launch_bounds__(256) void nchw_to_nhwc_bf16(
        const float* __restrict__ in, unsigned short* __restrict__ outp) {
    __shared__ unsigned short lds[64 * SROW];   // 64256 B
    const int s0 = blockIdx.x * ST;
    const int c0 = blockIdx.y * 64;
    const int b = blockIdx.z;
    const int tid = threadIdx.x;

    // fill: 64 channel rows x 125 float4, 2 KB contiguous per row
    const float* ibase = in + ((size_t)(b * FEAT_C + c0)) * FEAT_S + s0;
    for (int f = tid; f < 64 * ST4; f += 256) {
        int c = f / ST4;            // compile-time const divisor
        int j = f - c * ST4;
        float4 v = *(const float4*)(ibase + (size_t)c * FEAT_S + 4 * j);
        unsigned int p0 = (unsigned)f2bf(v.x) | ((unsigned)f2bf(v.y) << 16);
        unsigned int p1 = (unsigned)f2bf(v.z) | ((unsigned)f2bf(v.w) << 16);
        unsigned short* lp = &lds[c * SROW + 4 * j];
        *(unsigned int*)(lp) = p0;          // 4 B granular (keeps SROW*2 % 8 != 0 legal)
        *(unsigned int*)(lp + 2) = p1;
    }
    __syncthreads();

    // readout: for each spatial s, write 64 ch x 2 B = 128 B (8 x uint4)
    unsigned short* obase = outp + ((size_t)b * FEAT_S + s0) * FEAT_C + c0;
    for (int u = tid; u < ST * 8; u += 256) {
        int s = u >> 3;
        int m = u & 7;              // uint4 index: channels 8m..8m+7
        const unsigned short* lp = &lds[(8 * m) * SROW + s];
        unsigned int w0 = (unsigned)lp[0] | ((unsigned)lp[SROW] << 16);
        unsigned int w1 = (unsigned)lp[2 * SROW] | ((unsigned)lp[3 * SROW] << 16);
        unsigned int w2 = (unsigned)lp[4 * SROW] | ((unsigned)lp[5 * SROW] << 16);
        unsigned int w3 = (unsigned)lp[6 * SROW] | ((unsigned)lp[7 * SROW] << 16);
        uint4 o = make_uint4(w0, w1, w2, w3);
        *(uint4*)(obase + (size_t)s * FEAT_C + 8 * m) = o;
    }
}

// ---------- main: block = (roi, 64-channel quarter) ----------
__global__ __launch_bounds__(256) void roialign_main(
        const unsigned short* __restrict__ feat,   // [N,H,W,C] bf16
        const float* __restrict__ rois,
        float* __restrict__ out,
        int num_rois) {
    __shared__ float outbuf[64 * 49];              // 12544 B
    __shared__ int s_ylo[14], s_yhi[14], s_xlo[14], s_xhi[14];
    __shared__ float s_ywl[14], s_ywh[14], s_xwl[14], s_xwh[14];

    const int bid = blockIdx.x;
    const int roi = bid >> 2;
    const int qc = (bid & 3) * 64;                 // channel quarter base

    const float* r = rois + roi * 5;
    const int b = (int)r[0];
    const float x1 = r[1] * SPATIAL_SCALE;
    const float y1 = r[2] * SPATIAL_SCALE;
    const float x2 = r[3] * SPATIAL_SCALE;
    const float y2 = r[4] * SPATIAL_SCALE;
    const float bin_w = fmaxf(x2 - x1, 1.0f) * (1.0f / POOLED_W);
    const float bin_h = fmaxf(y2 - y1, 1.0f) * (1.0f / POOLED_H);

    const int tid = threadIdx.x;
    if (tid < 14) {
        int p = tid >> 1, i = tid & 1;
        float yy = y1 + (float)p * bin_h + ((float)i + 0.5f) * bin_h * 0.5f;
        bool v = (yy > -1.0f) && (yy < (float)FEAT_H);
        float y = fmaxf(yy, 0.0f);
        int lo = min((int)floorf(y), FEAT_H - 1);
        int hi = min(lo + 1, FEAT_H - 1);
        if (lo >= FEAT_H - 1) y = (float)lo;       // edge snap (reference-exact)
        float l = y - (float)lo;
        s_ylo[tid] = lo;
        s_yhi[tid] = hi;
        s_ywl[tid] = v ? l : 0.0f;                 // validity folded into weights
        s_ywh[tid] = v ? (1.0f - l) : 0.0f;
    } else if (tid >= 64 && tid < 78) {
        int tt = tid - 64;
        int p = tt >> 1, i = tt & 1;
        float xx = x1 + (float)p * bin_w + ((float)i + 0.5f) * bin_w * 0.5f;
        bool v = (xx > -1.0f) && (xx < (float)FEAT_W);
        float x = fmaxf(xx, 0.0f);
        int lo = min((int)floorf(x), FEAT_W - 1);
        int hi = min(lo + 1, FEAT_W - 1);
        if (lo >= FEAT_W - 1) x = (float)lo;
        float l = x - (float)lo;
        s_xlo[tt] = lo;
        s_xhi[tt] = hi;
        s_xwl[tt] = v ? l : 0.0f;
        s_xwh[tt] = v ? (1.0f - l) : 0.0f;
    }
    __syncthreads();

    const int Q = tid >> 4;          // quarter-wave 0..15: cells s = Q + 16k
    const int g = tid & 15;          // channel group: qc + 4g .. qc + 4g+3
    const unsigned short* base = feat + (size_t)b * IMG_USH + qc + 4 * g;

#pragma unroll
    for (int k = 0; k < 4; ++k) {
        const int s = Q + 16 * k;
        if (s < 49) {
            const int ph = (s * 37) >> 8;          // s/7 for s<49
            const int pw = s - ph * 7;
            float ax = 0.f, ay = 0.f, az = 0.f, aw = 0.f;
#pragma unroll
            for (int iy = 0; iy < 2; ++iy) {
                const int ky = ph * 2 + iy;
                const int rl = s_ylo[ky] * FEAT_W;
                const int rh = s_yhi[ky] * FEAT_W;
                const float wyl = s_ywl[ky];
                const float wyh = s_ywh[ky];
#pragma unroll
                for (int ix = 0; ix < 2; ++ix) {
                    const int kx = pw * 2 + ix;
                    const int cl = s_xlo[kx];
                    const int ch = s_xhi[kx];
                    const float w00 = wyh * s_xwh[kx];
                    const float w01 = wyh * s_xwl[kx];
                    const float w10 = wyl * s_xwh[kx];
                    const float w11 = wyl * s_xwl[kx];
                    uint2 t00 = *(const uint2*)(base + (size_t)(rl + cl) * FEAT_C);
                    uint2 t01 = *(const uint2*)(base + (size_t)(rl + ch) * FEAT_C);
                    uint2 t10 = *(const uint2*)(base + (size_t)(rh + cl) * FEAT_C);
                    uint2 t11 = *(const uint2*)(base + (size_t)(rh + ch) * FEAT_C);
                    // bf16 pair -> two fp32 (low = ch+0, high = ch+1)
                    ax += w00 * __uint_as_float(t00.x << 16) + w01 * __uint_as_float(t01.x << 16)
                        + w10 * __uint_as_float(t10.x << 16) + w11 * __uint_as_float(t11.x << 16);
                    ay += w00 * __uint_as_float(t00.x & 0xffff0000u) + w01 * __uint_as_float(t01.x & 0xffff0000u)
                        + w10 * __uint_as_float(t10.x & 0xffff0000u) + w11 * __uint_as_float(t11.x & 0xffff0000u);
                    az += w00 * __uint_as_float(t00.y << 16) + w01 * __uint_as_float(t01.y << 16)
                        + w10 * __uint_as_float(t10.y << 16) + w11 * __uint_as_float(t11.y << 16);
                    aw += w00 * __uint_as_float(t00.y & 0xffff0000u) + w01 * __uint_as_float(t01.y & 0xffff0000u)
                        + w10 * __uint_as_float(t10.y & 0xffff0000u) + w11 * __uint_as_float(t11.y & 0xffff0000u);
                }
            }
            outbuf[(4 * g + 0) * 49 + s] = ax * 0.25f;
            outbuf[(4 * g + 1) * 49 + s] = ay * 0.25f;
            outbuf[(4 * g + 2) * 49 + s] = az * 0.25f;
            outbuf[(4 * g + 3) * 49 + s] = aw * 0.25f;
        }
    }
    __syncthreads();

    // flat copy: 3136 floats = 784 float4, fully contiguous per block
    const float4* src = (const float4*)outbuf;
    float4* dst = (float4*)(out + (size_t)(roi * FEAT_C + qc) * 49);
    for (int i = tid; i < 784; i += 256) dst[i] = src[i];
}

// ---------- fallback (direct gather, no workspace) ----------
__device__ __forceinline__ float bilinear_tap(const float* __restrict__ plane,
                                              float y, float x) {
    const int H = FEAT_H, W = FEAT_W;
    if (!(y > -1.0f && y < (float)H && x > -1.0f && x < (float)W)) return 0.0f;
    y = fmaxf(y, 0.0f);
    x = fmaxf(x, 0.0f);
    int y0 = min((int)floorf(y), H - 1);
    int x0 = min((int)floorf(x), W - 1);
    int y1 = min(y0 + 1, H - 1);
    int x1 = min(x0 + 1, W - 1);
    if (y0 >= H - 1) y = (float)y0;
    if (x0 >= W - 1) x = (float)x0;
    float ly = y - (float)y0, lx = x - (float)x0;
    float hy = 1.0f - ly, hx = 1.0f - lx;
    return hy * (hx * plane[y0 * W + x0] + lx * plane[y0 * W + x1]) +
           ly * (hx * plane[y1 * W + x0] + lx * plane[y1 * W + x1]);
}

__global__ __launch_bounds__(256) void roialign_direct(
    const float* __restrict__ features, const float* __restrict__ rois,
    float* __restrict__ out, int num_rois) {
    int i = blockIdx.x * blockDim.x + threadIdx.x;
    int total = num_rois * FEAT_C * 49;
    if (i >= total) return;
    int s = i % 49;
    int t = i / 49;
    int c = t % FEAT_C;
    int roi = t / FEAT_C;
    int ph = s / POOLED_W, pw = s % POOLED_W;
    const float* r = rois + roi * 5;
    int b = (int)r[0];
    float x1 = r[1] * SPATIAL_SCALE, y1 = r[2] * SPATIAL_SCALE;
    float x2 = r[3] * SPATIAL_SCALE, y2 = r[4] * SPATIAL_SCALE;
    float bin_w = fmaxf(x2 - x1, 1.0f) * (1.0f / POOLED_W);
    float bin_h = fmaxf(y2 - y1, 1.0f) * (1.0f / POOLED_H);
    const float* plane = features + ((size_t)(b * FEAT_C + c)) * FEAT_S;
    float acc = 0.0f;
#pragma unroll
    for (int iy = 0; iy < 2; ++iy) {
        float yy = y1 + (float)ph * bin_h + ((float)iy + 0.5f) * bin_h * 0.5f;
#pragma unroll
        for (int ix = 0; ix < 2; ++ix) {
            float xx = x1 + (float)pw * bin_w + ((float)ix + 0.5f) * bin_w * 0.5f;
            acc += bilinear_tap(plane, yy, xx);
        }
    }
    out[i] = acc * 0.25f;
}

extern "C" void kernel_launch(void* const* d_in, const int* in_sizes, int n_in,
                              void* d_out, int out_size, void* d_ws, size_t ws_size,
                              hipStream_t stream) {
    const float* features = (const float*)d_in[0];
    const float* rois = (const float*)d_in[1];
    float* out = (float*)d_out;
    int num_rois = in_sizes[1] / 5;
    size_t need = (size_t)FEAT_N * IMG_USH * sizeof(unsigned short);  // ~41 MB
    if (ws_size >= need) {
        unsigned short* nhwc = (unsigned short*)d_ws;
        nchw_to_nhwc_bf16<<<dim3(FEAT_S / ST, FEAT_C / 64, FEAT_N), 256, 0, stream>>>(
            features, nhwc);
        roialign_main<<<num_rois * 4, 256, 0, stream>>>(nhwc, rois, out, num_rois);
    } else {
        int total = num_rois * FEAT_C * 49;
        roialign_direct<<<(total + 255) / 256, 256, 0, stream>>>(features, rois, out,
                                                                 num_rois);
    }
}

// Round 6
// 176.459 us; speedup vs baseline: 3.3589x; 1.0892x over previous
//
#include <hip/hip_runtime.h>

// RoIAlign forward, Detectron-style, sampling_ratio = 2.
// features: [N=2, C=256, H=200, W=200] fp32 ; rois: [1000,5] ; out: [1000,256,7,7]
//
// R6: R5's transpose was latency-bound at 13% occupancy (64.5 KB LDS -> 2
// blocks/CU, grid only 640). Retile to 32ch x 500sp: LDS 31.4 KB -> 5
// blocks/CU, grid 1280 (exactly 5/CU), reads stay 2 KB page runs, writes are
// full 64 B lines, LDS readout conflict-free. Main kernel (block = roi x
// 64-ch quarter, bf16 NHWC gather, LDS-staged flat stores) unchanged.

#define POOLED_H 7
#define POOLED_W 7
#define SPATIAL_SCALE 0.0625f
#define FEAT_N 2
#define FEAT_C 256
#define FEAT_H 200
#define FEAT_W 200
#define FEAT_S (FEAT_H * FEAT_W)               // 40000
#define IMG_USH ((size_t)FEAT_S * FEAT_C)      // ushorts per image in NHWC

// transpose tile: 32 channels x 500 spatial
#define ST 500            // spatial floats per tile (40000/500 = 80 exact)
#define ST4 (ST / 4)      // 125 float4 per channel row
#define CT 32             // channels per tile (256/32 = 8 exact)
#define SROW 502          // LDS row stride (ushorts), even; 32*502*2 = 32128 B

__device__ __forceinline__ unsigned short f2bf(float f) {
    unsigned int u = __float_as_uint(f);
    u += 0x7fffu + ((u >> 16) & 1u);   // round-to-nearest-even
    return (unsigned short)(u >> 16);
}

// ---------- NCHW fp32 -> NHWC bf16 ----------
__global__ __launch_bounds__(256) void nchw_to_nhwc_bf16(
        const float* __restrict__ in, unsigned short* __restrict__ outp) {
    __shared__ unsigned short lds[CT * SROW];   // 32128 B -> 5 blocks/CU
    const int s0 = blockIdx.x * ST;
    const int c0 = blockIdx.y * CT;
    const int b = blockIdx.z;
    const int tid = threadIdx.x;

    // fill: 32 channel rows x 125 float4 (2 KB contiguous per row)
    const float* ibase = in + ((size_t)(b * FEAT_C + c0)) * FEAT_S + s0;
    for (int f = tid; f < CT * ST4; f += 256) {
        int c = f / ST4;            // const divisor -> magic mul
        int j = f - c * ST4;
        float4 v = *(const float4*)(ibase + (size_t)c * FEAT_S + 4 * j);
        unsigned int p0 = (unsigned)f2bf(v.x) | ((unsigned)f2bf(v.y) << 16);
        unsigned int p1 = (unsigned)f2bf(v.z) | ((unsigned)f2bf(v.w) << 16);
        unsigned short* lp = &lds[c * SROW + 4 * j];
        *(unsigned int*)(lp) = p0;
        *(unsigned int*)(lp + 2) = p1;
    }
    __syncthreads();

    // readout: per spatial s, 32 ch x 2 B = one full 64 B line (4 x uint4).
    // lanes vary along s within fixed m -> conflict-free LDS banks, and
    // each uint4 store lands in a line fully covered by this block.
    unsigned short* obase = outp + ((size_t)b * FEAT_S + s0) * FEAT_C + c0;
#pragma unroll
    for (int m = 0; m < 4; ++m) {               // uint4 index: channels 8m..8m+7
        for (int s = tid; s < ST; s += 256) {
            const unsigned short* lp = &lds[(8 * m) * SROW + s];
            unsigned int w0 = (unsigned)lp[0] | ((unsigned)lp[SROW] << 16);
            unsigned int w1 = (unsigned)lp[2 * SROW] | ((unsigned)lp[3 * SROW] << 16);
            unsigned int w2 = (unsigned)lp[4 * SROW] | ((unsigned)lp[5 * SROW] << 16);
            unsigned int w3 = (unsigned)lp[6 * SROW] | ((unsigned)lp[7 * SROW] << 16);
            *(uint4*)(obase + (size_t)s * FEAT_C + 8 * m) = make_uint4(w0, w1, w2, w3);
        }
    }
}

// ---------- main: block = (roi, 64-channel quarter) ----------
__global__ __launch_bounds__(256) void roialign_main(
        const unsigned short* __restrict__ feat,   // [N,H,W,C] bf16
        const float* __restrict__ rois,
        float* __restrict__ out,
        int num_rois) {
    __shared__ float outbuf[64 * 49];              // 12544 B
    __shared__ int s_ylo[14], s_yhi[14], s_xlo[14], s_xhi[14];
    __shared__ float s_ywl[14], s_ywh[14], s_xwl[14], s_xwh[14];

    const int bid = blockIdx.x;
    const int roi = bid >> 2;
    const int qc = (bid & 3) * 64;                 // channel quarter base

    const float* r = rois + roi * 5;
    const int b = (int)r[0];
    const float x1 = r[1] * SPATIAL_SCALE;
    const float y1 = r[2] * SPATIAL_SCALE;
    const float x2 = r[3] * SPATIAL_SCALE;
    const float y2 = r[4] * SPATIAL_SCALE;
    const float bin_w = fmaxf(x2 - x1, 1.0f) * (1.0f / POOLED_W);
    const float bin_h = fmaxf(y2 - y1, 1.0f) * (1.0f / POOLED_H);

    const int tid = threadIdx.x;
    if (tid < 14) {
        int p = tid >> 1, i = tid & 1;
        float yy = y1 + (float)p * bin_h + ((float)i + 0.5f) * bin_h * 0.5f;
        bool v = (yy > -1.0f) && (yy < (float)FEAT_H);
        float y = fmaxf(yy, 0.0f);
        int lo = min((int)floorf(y), FEAT_H - 1);
        int hi = min(lo + 1, FEAT_H - 1);
        if (lo >= FEAT_H - 1) y = (float)lo;       // edge snap (reference-exact)
        float l = y - (float)lo;
        s_ylo[tid] = lo;
        s_yhi[tid] = hi;
        s_ywl[tid] = v ? l : 0.0f;                 // validity folded into weights
        s_ywh[tid] = v ? (1.0f - l) : 0.0f;
    } else if (tid >= 64 && tid < 78) {
        int tt = tid - 64;
        int p = tt >> 1, i = tt & 1;
        float xx = x1 + (float)p * bin_w + ((float)i + 0.5f) * bin_w * 0.5f;
        bool v = (xx > -1.0f) && (xx < (float)FEAT_W);
        float x = fmaxf(xx, 0.0f);
        int lo = min((int)floorf(x), FEAT_W - 1);
        int hi = min(lo + 1, FEAT_W - 1);
        if (lo >= FEAT_W - 1) x = (float)lo;
        float l = x - (float)lo;
        s_xlo[tt] = lo;
        s_xhi[tt] = hi;
        s_xwl[tt] = v ? l : 0.0f;
        s_xwh[tt] = v ? (1.0f - l) : 0.0f;
    }
    __syncthreads();

    const int Q = tid >> 4;          // quarter-wave 0..15: cells s = Q + 16k
    const int g = tid & 15;          // channel group: qc + 4g .. qc + 4g+3
    const unsigned short* base = feat + (size_t)b * IMG_USH + qc + 4 * g;

#pragma unroll
    for (int k = 0; k < 4; ++k) {
        const int s = Q + 16 * k;
        if (s < 49) {
            const int ph = (s * 37) >> 8;          // s/7 for s<49
            const int pw = s - ph * 7;
            float ax = 0.f, ay = 0.f, az = 0.f, aw = 0.f;
#pragma unroll
            for (int iy = 0; iy < 2; ++iy) {
                const int ky = ph * 2 + iy;
                const int rl = s_ylo[ky] * FEAT_W;
                const int rh = s_yhi[ky] * FEAT_W;
                const float wyl = s_ywl[ky];
                const float wyh = s_ywh[ky];
#pragma unroll
                for (int ix = 0; ix < 2; ++ix) {
                    const int kx = pw * 2 + ix;
                    const int cl = s_xlo[kx];
                    const int ch = s_xhi[kx];
                    const float w00 = wyh * s_xwh[kx];
                    const float w01 = wyh * s_xwl[kx];
                    const float w10 = wyl * s_xwh[kx];
                    const float w11 = wyl * s_xwl[kx];
                    uint2 t00 = *(const uint2*)(base + (size_t)(rl + cl) * FEAT_C);
                    uint2 t01 = *(const uint2*)(base + (size_t)(rl + ch) * FEAT_C);
                    uint2 t10 = *(const uint2*)(base + (size_t)(rh + cl) * FEAT_C);
                    uint2 t11 = *(const uint2*)(base + (size_t)(rh + ch) * FEAT_C);
                    ax += w00 * __uint_as_float(t00.x << 16) + w01 * __uint_as_float(t01.x << 16)
                        + w10 * __uint_as_float(t10.x << 16) + w11 * __uint_as_float(t11.x << 16);
                    ay += w00 * __uint_as_float(t00.x & 0xffff0000u) + w01 * __uint_as_float(t01.x & 0xffff0000u)
                        + w10 * __uint_as_float(t10.x & 0xffff0000u) + w11 * __uint_as_float(t11.x & 0xffff0000u);
                    az += w00 * __uint_as_float(t00.y << 16) + w01 * __uint_as_float(t01.y << 16)
                        + w10 * __uint_as_float(t10.y << 16) + w11 * __uint_as_float(t11.y << 16);
                    aw += w00 * __uint_as_float(t00.y & 0xffff0000u) + w01 * __uint_as_float(t01.y & 0xffff0000u)
                        + w10 * __uint_as_float(t10.y & 0xffff0000u) + w11 * __uint_as_float(t11.y & 0xffff0000u);
                }
            }
            outbuf[(4 * g + 0) * 49 + s] = ax * 0.25f;
            outbuf[(4 * g + 1) * 49 + s] = ay * 0.25f;
            outbuf[(4 * g + 2) * 49 + s] = az * 0.25f;
            outbuf[(4 * g + 3) * 49 + s] = aw * 0.25f;
        }
    }
    __syncthreads();

    // flat copy: 3136 floats = 784 float4, fully contiguous per block
    const float4* src = (const float4*)outbuf;
    float4* dst = (float4*)(out + (size_t)(roi * FEAT_C + qc) * 49);
    for (int i = tid; i < 784; i += 256) dst[i] = src[i];
}

// ---------- fallback (direct gather, no workspace) ----------
__device__ __forceinline__ float bilinear_tap(const float* __restrict__ plane,
                                              float y, float x) {
    const int H = FEAT_H, W = FEAT_W;
    if (!(y > -1.0f && y < (float)H && x > -1.0f && x < (float)W)) return 0.0f;
    y = fmaxf(y, 0.0f);
    x = fmaxf(x, 0.0f);
    int y0 = min((int)floorf(y), H - 1);
    int x0 = min((int)floorf(x), W - 1);
    int y1 = min(y0 + 1, H - 1);
    int x1 = min(x0 + 1, W - 1);
    if (y0 >= H - 1) y = (float)y0;
    if (x0 >= W - 1) x = (float)x0;
    float ly = y - (float)y0, lx = x - (float)x0;
    float hy = 1.0f - ly, hx = 1.0f - lx;
    return hy * (hx * plane[y0 * W + x0] + lx * plane[y0 * W + x1]) +
           ly * (hx * plane[y1 * W + x0] + lx * plane[y1 * W + x1]);
}

__global__ __launch_bounds__(256) void roialign_direct(
    const float* __restrict__ features, const float* __restrict__ rois,
    float* __restrict__ out, int num_rois) {
    int i = blockIdx.x * blockDim.x + threadIdx.x;
    int total = num_rois * FEAT_C * 49;
    if (i >= total) return;
    int s = i % 49;
    int t = i / 49;
    int c = t % FEAT_C;
    int roi = t / FEAT_C;
    int ph = s / POOLED_W, pw = s % POOLED_W;
    const float* r = rois + roi * 5;
    int b = (int)r[0];
    float x1 = r[1] * SPATIAL_SCALE, y1 = r[2] * SPATIAL_SCALE;
    float x2 = r[3] * SPATIAL_SCALE, y2 = r[4] * SPATIAL_SCALE;
    float bin_w = fmaxf(x2 - x1, 1.0f) * (1.0f / POOLED_W);
    float bin_h = fmaxf(y2 - y1, 1.0f) * (1.0f / POOLED_H);
    const float* plane = features + ((size_t)(b * FEAT_C + c)) * FEAT_S;
    float acc = 0.0f;
#pragma unroll
    for (int iy = 0; iy < 2; ++iy) {
        float yy = y1 + (float)ph * bin_h + ((float)iy + 0.5f) * bin_h * 0.5f;
#pragma unroll
        for (int ix = 0; ix < 2; ++ix) {
            float xx = x1 + (float)pw * bin_w + ((float)ix + 0.5f) * bin_w * 0.5f;
            acc += bilinear_tap(plane, yy, xx);
        }
    }
    out[i] = acc * 0.25f;
}

extern "C" void kernel_launch(void* const* d_in, const int* in_sizes, int n_in,
                              void* d_out, int out_size, void* d_ws, size_t ws_size,
                              hipStream_t stream) {
    const float* features = (const float*)d_in[0];
    const float* rois = (const float*)d_in[1];
    float* out = (float*)d_out;
    int num_rois = in_sizes[1] / 5;
    size_t need = (size_t)FEAT_N * IMG_USH * sizeof(unsigned short);  // ~41 MB
    if (ws_size >= need) {
        unsigned short* nhwc = (unsigned short*)d_ws;
        nchw_to_nhwc_bf16<<<dim3(FEAT_S / ST, FEAT_C / CT, FEAT_N), 256, 0, stream>>>(
            features, nhwc);
        roialign_main<<<num_rois * 4, 256, 0, stream>>>(nhwc, rois, out, num_rois);
    } else {
        int total = num_rois * FEAT_C * 49;
        roialign_direct<<<(total + 255) / 256, 256, 0, stream>>>(features, rois, out,
                                                                 num_rois);
    }
}